// Round 1
// baseline (441.209 us; speedup 1.0000x reference)
//
#include <hip/hip_runtime.h>
#include <cstdint>
#include <cstddef>

#define BB 64
#define PP 24564
#define OO 16
#define NC 21
#define TPB 256
#define TPD 1024
#define NPT 24  /* ceil(PP/TPD) */

// ---------------- workspace layout (bytes) ----------------
// [0,16)            double acc[2]  : acc[0]=loss_l_sum, acc[1]=loss_c_sum
// [64,64+4*BB)      int num_pos[BB]
// [1024,1024+8*BB*OO) u64 keys[BB*OO]   (packed per-truth best prior)
// [16384, +4*BB*PP) float bto[BB*PP]    (best_truth_overlap)
// next   (+4*BB*PP) int   bti[BB*PP]    (best_truth_idx)
// next   (+4*BB*PP) float lh[BB*PP]     (loss_hard)
static constexpr size_t OFF_ACC  = 0;
static constexpr size_t OFF_NP   = 64;
static constexpr size_t OFF_KEYS = 1024;
static constexpr size_t OFF_BTO  = 16384;
static constexpr size_t SZ_BP    = (size_t)BB * PP * 4;
static constexpr size_t OFF_BTI  = OFF_BTO + SZ_BP;
static constexpr size_t OFF_LH   = OFF_BTI + SZ_BP;

// ---------------- Pass A: per-(b,p) IoU vs 16 truths ----------------
__global__ __launch_bounds__(TPB) void match_kernel(
    const float* __restrict__ priors, const float* __restrict__ targets,
    float* __restrict__ bto, int* __restrict__ bti,
    unsigned long long* __restrict__ keys) {
  const int b = blockIdx.y;
  const int p = blockIdx.x * TPB + threadIdx.x;
  __shared__ float tr[OO * 5];
  __shared__ unsigned long long red[TPB / 64];
  if (threadIdx.x < OO * 5) tr[threadIdx.x] = targets[b * OO * 5 + threadIdx.x];
  __syncthreads();

  const bool valid = p < PP;
  float ax1 = 0.f, ay1 = 0.f, ax2 = 0.f, ay2 = 0.f, area_p = 0.f;
  if (valid) {
    float4 pr = reinterpret_cast<const float4*>(priors)[p];
    ax1 = pr.x - pr.z * 0.5f; ay1 = pr.y - pr.w * 0.5f;
    ax2 = pr.x + pr.z * 0.5f; ay2 = pr.y + pr.w * 0.5f;
    area_p = (ax2 - ax1) * (ay2 - ay1);
  }

  float best = -1.0f; int besti = 0;
  const int lane = threadIdx.x & 63, wid = threadIdx.x >> 6;

  for (int t = 0; t < OO; ++t) {
    const float tx1 = tr[t * 5 + 0], ty1 = tr[t * 5 + 1];
    const float tx2 = tr[t * 5 + 2], ty2 = tr[t * 5 + 3];
    float iou = 0.f;
    if (valid) {
      float lx = fmaxf(tx1, ax1), ly = fmaxf(ty1, ay1);
      float rx = fminf(tx2, ax2), ry = fminf(ty2, ay2);
      float iw = fmaxf(rx - lx, 0.f), ih = fmaxf(ry - ly, 0.f);
      float inter = iw * ih;
      float area_t = (tx2 - tx1) * (ty2 - ty1);
      iou = inter / (area_t + area_p - inter);
      if (iou > best) { best = iou; besti = t; }  // first-max wins (ascending t, strict >)
    }
    // packed key: higher iou wins; on tie, lower prior index wins
    unsigned long long key = valid
        ? (((unsigned long long)__float_as_uint(iou) << 32) |
           (unsigned long long)(0xFFFFFFFFu - (unsigned)p))
        : 0ull;
    for (int off = 32; off; off >>= 1) {
      unsigned long long o = __shfl_down(key, off, 64);
      if (o > key) key = o;
    }
    if (lane == 0) red[wid] = key;
    __syncthreads();
    if (threadIdx.x == 0) {
      unsigned long long m = red[0];
      for (int i = 1; i < TPB / 64; ++i) if (red[i] > m) m = red[i];
      atomicMax(&keys[b * OO + t], m);
    }
    __syncthreads();
  }
  if (valid) { bto[(size_t)b * PP + p] = best; bti[(size_t)b * PP + p] = besti; }
}

// ---------------- Pass B: force-match scatter (sequential, last-wins) ----------------
__global__ void force_kernel(const unsigned long long* __restrict__ keys,
                             float* __restrict__ bto, int* __restrict__ bti) {
  const int b = threadIdx.x;
  if (b >= BB) return;
  for (int j = 0; j < OO; ++j) {
    unsigned long long k = keys[b * OO + j];
    unsigned p = 0xFFFFFFFFu - (unsigned)(k & 0xFFFFFFFFu);
    if (p < PP) {
      bto[(size_t)b * PP + p] = 2.0f;
      bti[(size_t)b * PP + p] = j;
    }
  }
}

// ---------------- Pass C: CE + smooth-L1 + loss_hard ----------------
__global__ __launch_bounds__(TPB) void loss_kernel(
    const float* __restrict__ loc, const float* __restrict__ conf,
    const float* __restrict__ priors, const float* __restrict__ targets,
    const float* __restrict__ bto, const int* __restrict__ bti,
    float* __restrict__ lh, double* __restrict__ acc, int* __restrict__ num_pos) {
  const int b = blockIdx.y;
  const int p0 = blockIdx.x * TPB;
  const int p = p0 + threadIdx.x;
  __shared__ float sc[TPB * NC];
  __shared__ float tr[OO * 5];
  __shared__ float rc[TPB / 64], rl[TPB / 64];
  __shared__ int rn[TPB / 64];
  if (threadIdx.x < OO * 5) tr[threadIdx.x] = targets[b * OO * 5 + threadIdx.x];
  const int nvalid = min(TPB, PP - p0);
  const float* cbase = conf + ((size_t)b * PP + p0) * NC;
  for (int i = threadIdx.x; i < nvalid * NC; i += TPB) sc[i] = cbase[i];
  __syncthreads();

  float ce = 0.f, l_part = 0.f;
  bool pos = false;
  if (p < PP) {
    const float* cv = &sc[threadIdx.x * NC];
    float m = cv[0];
    #pragma unroll
    for (int i = 1; i < NC; ++i) m = fmaxf(m, cv[i]);
    float s = 0.f;
    #pragma unroll
    for (int i = 0; i < NC; ++i) s += expf(cv[i] - m);
    float lse = m + logf(s);

    float ov = bto[(size_t)b * PP + p];
    int t = bti[(size_t)b * PP + p];
    int lbl = (int)tr[t * 5 + 4];
    int c = (ov < 0.5f) ? 0 : (lbl + 1);
    ce = lse - cv[c];
    pos = (c > 0);
    lh[(size_t)b * PP + p] = pos ? 0.f : ce;

    if (pos) {
      float tx1 = tr[t * 5 + 0], ty1 = tr[t * 5 + 1];
      float tx2 = tr[t * 5 + 2], ty2 = tr[t * 5 + 3];
      float4 pr = reinterpret_cast<const float4*>(priors)[p];
      float g0 = ((tx1 + tx2) * 0.5f - pr.x) / (0.1f * pr.z);
      float g1 = ((ty1 + ty2) * 0.5f - pr.y) / (0.1f * pr.w);
      float g2 = logf((tx2 - tx1) / pr.z) / 0.2f;
      float g3 = logf((ty2 - ty1) / pr.w) / 0.2f;
      float4 lv = reinterpret_cast<const float4*>(loc)[(size_t)b * PP + p];
      float g[4] = {g0, g1, g2, g3};
      float l[4] = {lv.x, lv.y, lv.z, lv.w};
      #pragma unroll
      for (int i = 0; i < 4; ++i) {
        float d = l[i] - g[i];
        float ad = fabsf(d);
        l_part += (ad < 1.f) ? 0.5f * d * d : (ad - 0.5f);
      }
    }
  }

  float cp = pos ? ce : 0.f;
  int cnt = pos ? 1 : 0;
  for (int off = 32; off; off >>= 1) {
    cp += __shfl_down(cp, off, 64);
    l_part += __shfl_down(l_part, off, 64);
    cnt += __shfl_down(cnt, off, 64);
  }
  const int lane = threadIdx.x & 63, wid = threadIdx.x >> 6;
  if (lane == 0) { rc[wid] = cp; rl[wid] = l_part; rn[wid] = cnt; }
  __syncthreads();
  if (threadIdx.x == 0) {
    float csum = 0.f, lsum = 0.f; int n = 0;
    for (int i = 0; i < TPB / 64; ++i) { csum += rc[i]; lsum += rl[i]; n += rn[i]; }
    if (lsum != 0.f) atomicAdd(&acc[0], (double)lsum);
    if (csum != 0.f) atomicAdd(&acc[1], (double)csum);
    if (n) atomicAdd(&num_pos[b], n);
  }
}

// ---------------- Pass D: per-batch top-K sum of loss_hard ----------------
__global__ __launch_bounds__(TPD) void topk_kernel(
    const float* __restrict__ lh, const int* __restrict__ num_pos,
    double* __restrict__ acc) {
  const int b = blockIdx.x;
  const int np = num_pos[b];
  const int K = min(3 * np, PP - 1);
  if (K <= 0) return;

  unsigned bits[NPT];
  const float* base = lh + (size_t)b * PP;
  #pragma unroll
  for (int i = 0; i < NPT; ++i) {
    int idx = threadIdx.x + i * TPD;
    bits[i] = (idx < PP) ? __float_as_uint(base[idx]) : 0u;
  }

  __shared__ int rcnt[TPD / 64];
  __shared__ int bfl;
  const int lane = threadIdx.x & 63, wid = threadIdx.x >> 6;

  // find bits of the K-th largest value: largest T with count(bits>=T) >= K
  unsigned lo = 0u, hi = 0x7F800000u;  // f(lo)=true (all P>=K), f(inf)=false
  while (lo < hi) {
    unsigned mid = lo + (hi - lo + 1) / 2;  // >= 1
    int c = 0;
    #pragma unroll
    for (int i = 0; i < NPT; ++i) c += (bits[i] >= mid) ? 1 : 0;
    for (int off = 32; off; off >>= 1) c += __shfl_down(c, off, 64);
    if (lane == 0) rcnt[wid] = c;
    __syncthreads();
    if (threadIdx.x == 0) {
      int tot = 0;
      for (int i = 0; i < TPD / 64; ++i) tot += rcnt[i];
      bfl = (tot >= K) ? 1 : 0;
    }
    __syncthreads();
    if (bfl) lo = mid; else hi = mid - 1;
    __syncthreads();
  }
  const unsigned Tk = lo;
  const float vk = __uint_as_float(Tk);

  float s = 0.f; int cgt = 0;
  #pragma unroll
  for (int i = 0; i < NPT; ++i) {
    if (bits[i] > Tk) { s += __uint_as_float(bits[i]); ++cgt; }
  }
  double sd = (double)s;
  for (int off = 32; off; off >>= 1) {
    sd += __shfl_down(sd, off, 64);
    cgt += __shfl_down(cgt, off, 64);
  }
  __shared__ double rs[TPD / 64];
  __shared__ int rg[TPD / 64];
  if (lane == 0) { rs[wid] = sd; rg[wid] = cgt; }
  __syncthreads();
  if (threadIdx.x == 0) {
    double S = 0.0; int CG = 0;
    for (int i = 0; i < TPD / 64; ++i) { S += rs[i]; CG += rg[i]; }
    double contrib = S + (double)vk * (double)(K - CG);
    atomicAdd(&acc[1], contrib);
  }
}

// ---------------- Pass E: finalize ----------------
__global__ void final_kernel(const double* __restrict__ acc,
                             const int* __restrict__ num_pos,
                             float* __restrict__ out) {
  int n = (threadIdx.x < BB) ? num_pos[threadIdx.x] : 0;
  for (int off = 32; off; off >>= 1) n += __shfl_down(n, off, 64);
  if (threadIdx.x == 0) {
    double N = (double)max(n, 1);
    out[0] = (float)(acc[0] / N);
    out[1] = (float)(acc[1] / N);
  }
}

extern "C" void kernel_launch(void* const* d_in, const int* in_sizes, int n_in,
                              void* d_out, int out_size, void* d_ws, size_t ws_size,
                              hipStream_t stream) {
  const float* loc     = (const float*)d_in[0];  // B*P*4
  const float* conf    = (const float*)d_in[1];  // B*P*21
  const float* priors  = (const float*)d_in[2];  // P*4
  const float* targets = (const float*)d_in[3];  // B*O*5
  float* out = (float*)d_out;

  char* ws = (char*)d_ws;
  double* acc = (double*)(ws + OFF_ACC);
  int* num_pos = (int*)(ws + OFF_NP);
  unsigned long long* keys = (unsigned long long*)(ws + OFF_KEYS);
  float* bto = (float*)(ws + OFF_BTO);
  int* bti = (int*)(ws + OFF_BTI);
  float* lh = (float*)(ws + OFF_LH);

  // zero accumulators + keys + num_pos
  hipMemsetAsync(ws, 0, 16384, stream);

  dim3 gridA((PP + TPB - 1) / TPB, BB);
  match_kernel<<<gridA, TPB, 0, stream>>>(priors, targets, bto, bti, keys);
  force_kernel<<<1, BB, 0, stream>>>(keys, bto, bti);
  loss_kernel<<<gridA, TPB, 0, stream>>>(loc, conf, priors, targets, bto, bti,
                                         lh, acc, num_pos);
  topk_kernel<<<BB, TPD, 0, stream>>>(lh, num_pos, acc);
  final_kernel<<<1, 64, 0, stream>>>(acc, num_pos, out);
}

// Round 2
// 296.476 us; speedup vs baseline: 1.4882x; 1.4882x over previous
//
#include <hip/hip_runtime.h>
#include <cstdint>
#include <cstddef>

#define BB 64
#define PP 24564
#define OO 16
#define NC 21
#define TPB 256
#define TPD 1024
#define NPT 24  /* ceil(PP/TPD) for topk */

// match kernel geometry
#define MB 4     /* blocks per batch */
#define MT 1024  /* threads per match block */
#define MPT 6    /* priors per thread: MB*MT*MPT = 24576 >= PP */

// ---------------- workspace layout (bytes) ----------------
static constexpr size_t OFF_ACCL = 0;      // double[64]
static constexpr size_t OFF_ACCC = 512;    // double[64]
static constexpr size_t OFF_TOPC = 1024;   // double[64]
static constexpr size_t OFF_NP   = 1536;   // int[64]
static constexpr size_t OFF_KEYS = 2048;   // u64[BB*OO] = 8192 B
static constexpr size_t OFF_LH   = 16384;  // float[BB*PP]
// memset range: [0, 12288)

// ---------------- Pass A: per-truth best prior (keys only) ----------------
__global__ __launch_bounds__(MT) void match_kernel(
    const float* __restrict__ priors, const float* __restrict__ targets,
    unsigned long long* __restrict__ keys) {
  const int b = blockIdx.y;
  const int bx = blockIdx.x;
  __shared__ float tr[OO * 5];
  __shared__ unsigned long long red[16 * OO];  // [t][wave]
  if (threadIdx.x < OO * 5) tr[threadIdx.x] = targets[b * OO * 5 + threadIdx.x];
  __syncthreads();

  unsigned long long k16[OO];
  #pragma unroll
  for (int t = 0; t < OO; ++t) k16[t] = 0ull;

  #pragma unroll
  for (int i = 0; i < MPT; ++i) {
    const int p = bx * MT + threadIdx.x + i * (MB * MT);
    if (p < PP) {
      float4 pr = reinterpret_cast<const float4*>(priors)[p];
      float ax1 = pr.x - pr.z * 0.5f, ay1 = pr.y - pr.w * 0.5f;
      float ax2 = pr.x + pr.z * 0.5f, ay2 = pr.y + pr.w * 0.5f;
      float area_p = (ax2 - ax1) * (ay2 - ay1);
      const unsigned long long plo =
          (unsigned long long)(0xFFFFFFFFu - (unsigned)p);
      #pragma unroll
      for (int t = 0; t < OO; ++t) {
        float tx1 = tr[t * 5 + 0], ty1 = tr[t * 5 + 1];
        float tx2 = tr[t * 5 + 2], ty2 = tr[t * 5 + 3];
        float lx = fmaxf(tx1, ax1), ly = fmaxf(ty1, ay1);
        float rx = fminf(tx2, ax2), ry = fminf(ty2, ay2);
        float iw = fmaxf(rx - lx, 0.f), ih = fmaxf(ry - ly, 0.f);
        float inter = iw * ih;
        float area_t = (tx2 - tx1) * (ty2 - ty1);
        float iou = inter / (area_t + area_p - inter);
        unsigned long long key =
            ((unsigned long long)__float_as_uint(iou) << 32) | plo;
        if (key > k16[t]) k16[t] = key;
      }
    }
  }

  const int lane = threadIdx.x & 63, wid = threadIdx.x >> 6;
  #pragma unroll
  for (int t = 0; t < OO; ++t) {
    unsigned long long k = k16[t];
    for (int off = 32; off; off >>= 1) {
      unsigned long long o = __shfl_down(k, off, 64);
      if (o > k) k = o;
    }
    if (lane == 0) red[t * 16 + wid] = k;
  }
  __syncthreads();
  if (threadIdx.x < OO) {
    unsigned long long m = red[threadIdx.x * 16];
    #pragma unroll
    for (int w = 1; w < 16; ++w) {
      unsigned long long o = red[threadIdx.x * 16 + w];
      if (o > m) m = o;
    }
    atomicMax(&keys[b * OO + threadIdx.x], m);
  }
}

// ---------------- Pass B: CE + smooth-L1 + loss_hard (match recomputed) ----
__global__ __launch_bounds__(TPB) void loss_kernel(
    const float* __restrict__ loc, const float* __restrict__ conf,
    const float* __restrict__ priors, const float* __restrict__ targets,
    const unsigned long long* __restrict__ keys,
    float* __restrict__ lh, double* __restrict__ accL,
    double* __restrict__ accC, int* __restrict__ num_pos) {
  const int b = blockIdx.y;
  const int p0 = blockIdx.x * TPB;
  const int p = p0 + threadIdx.x;
  __shared__ float sc[TPB * NC];
  __shared__ float tr[OO * 5];
  __shared__ int fp[OO];
  __shared__ float rc[TPB / 64], rl[TPB / 64];
  __shared__ int rn[TPB / 64];
  if (threadIdx.x < OO * 5) tr[threadIdx.x] = targets[b * OO * 5 + threadIdx.x];
  if (threadIdx.x < OO) {
    unsigned long long k = keys[b * OO + threadIdx.x];
    unsigned pp = 0xFFFFFFFFu - (unsigned)(k & 0xFFFFFFFFu);
    fp[threadIdx.x] = (pp < PP) ? (int)pp : -1;
  }
  const int nvalid = min(TPB, PP - p0);
  {
    const float4* cb4 =
        reinterpret_cast<const float4*>(conf + ((size_t)b * PP + p0) * NC);
    float4* sc4 = reinterpret_cast<float4*>(sc);
    const int n4 = nvalid * NC / 4;  // nvalid % 4 == 0 always (256 or 244)
    for (int i = threadIdx.x; i < n4; i += TPB) sc4[i] = cb4[i];
  }
  __syncthreads();

  float ce = 0.f, l_part = 0.f;
  bool pos = false;
  if (p < PP) {
    float4 pr = reinterpret_cast<const float4*>(priors)[p];
    float ax1 = pr.x - pr.z * 0.5f, ay1 = pr.y - pr.w * 0.5f;
    float ax2 = pr.x + pr.z * 0.5f, ay2 = pr.y + pr.w * 0.5f;
    float area_p = (ax2 - ax1) * (ay2 - ay1);
    float best = -1.0f; int bt = 0;
    #pragma unroll
    for (int t = 0; t < OO; ++t) {
      float tx1 = tr[t * 5 + 0], ty1 = tr[t * 5 + 1];
      float tx2 = tr[t * 5 + 2], ty2 = tr[t * 5 + 3];
      float lx = fmaxf(tx1, ax1), ly = fmaxf(ty1, ay1);
      float rx = fminf(tx2, ax2), ry = fminf(ty2, ay2);
      float iw = fmaxf(rx - lx, 0.f), ih = fmaxf(ry - ly, 0.f);
      float inter = iw * ih;
      float area_t = (tx2 - tx1) * (ty2 - ty1);
      float iou = inter / (area_t + area_p - inter);
      if (iou > best) { best = iou; bt = t; }  // first-max wins
    }
    float ov = best; int t = bt;
    #pragma unroll
    for (int j = 0; j < OO; ++j) {  // ascending, last-wins (matches scatter)
      if (fp[j] == p) { ov = 2.0f; t = j; }
    }

    const float* cv = &sc[threadIdx.x * NC];
    float m = cv[0];
    #pragma unroll
    for (int i = 1; i < NC; ++i) m = fmaxf(m, cv[i]);
    float s = 0.f;
    #pragma unroll
    for (int i = 0; i < NC; ++i) s += expf(cv[i] - m);
    float lse = m + logf(s);

    int lbl = (int)tr[t * 5 + 4];
    int c = (ov < 0.5f) ? 0 : (lbl + 1);
    ce = lse - cv[c];
    pos = (c > 0);
    lh[(size_t)b * PP + p] = pos ? 0.f : ce;

    if (pos) {
      float tx1 = tr[t * 5 + 0], ty1 = tr[t * 5 + 1];
      float tx2 = tr[t * 5 + 2], ty2 = tr[t * 5 + 3];
      float g0 = ((tx1 + tx2) * 0.5f - pr.x) / (0.1f * pr.z);
      float g1 = ((ty1 + ty2) * 0.5f - pr.y) / (0.1f * pr.w);
      float g2 = logf((tx2 - tx1) / pr.z) / 0.2f;
      float g3 = logf((ty2 - ty1) / pr.w) / 0.2f;
      float4 lv = reinterpret_cast<const float4*>(loc)[(size_t)b * PP + p];
      float g[4] = {g0, g1, g2, g3};
      float l[4] = {lv.x, lv.y, lv.z, lv.w};
      #pragma unroll
      for (int i = 0; i < 4; ++i) {
        float d = l[i] - g[i];
        float ad = fabsf(d);
        l_part += (ad < 1.f) ? 0.5f * d * d : (ad - 0.5f);
      }
    }
  }

  float cp = pos ? ce : 0.f;
  int cnt = pos ? 1 : 0;
  for (int off = 32; off; off >>= 1) {
    cp += __shfl_down(cp, off, 64);
    l_part += __shfl_down(l_part, off, 64);
    cnt += __shfl_down(cnt, off, 64);
  }
  const int lane = threadIdx.x & 63, wid = threadIdx.x >> 6;
  if (lane == 0) { rc[wid] = cp; rl[wid] = l_part; rn[wid] = cnt; }
  __syncthreads();
  if (threadIdx.x == 0) {
    float csum = 0.f, lsum = 0.f; int n = 0;
    for (int i = 0; i < TPB / 64; ++i) { csum += rc[i]; lsum += rl[i]; n += rn[i]; }
    if (lsum != 0.f) atomicAdd(&accL[b], (double)lsum);
    if (csum != 0.f) atomicAdd(&accC[b], (double)csum);
    if (n) atomicAdd(&num_pos[b], n);
  }
}

// ---------------- Pass C: per-batch top-K sum of loss_hard ----------------
__global__ __launch_bounds__(TPD) void topk_kernel(
    const float* __restrict__ lh, const int* __restrict__ num_pos,
    double* __restrict__ topC) {
  const int b = blockIdx.x;
  const int np = num_pos[b];
  const int K = min(3 * np, PP - 1);
  if (K <= 0) {
    if (threadIdx.x == 0) topC[b] = 0.0;
    return;
  }

  unsigned bits[NPT];
  const float* base = lh + (size_t)b * PP;
  #pragma unroll
  for (int i = 0; i < NPT; ++i) {
    int idx = threadIdx.x + i * TPD;
    bits[i] = (idx < PP) ? __float_as_uint(base[idx]) : 0u;
  }

  __shared__ int rcnt[TPD / 64];
  __shared__ int bfl;
  const int lane = threadIdx.x & 63, wid = threadIdx.x >> 6;

  // largest T with count(bits >= T) >= K  → T = bits of K-th largest
  unsigned lo = 0u, hi = 0x7F800000u;
  while (lo < hi) {
    unsigned mid = lo + (hi - lo + 1) / 2;
    int c = 0;
    #pragma unroll
    for (int i = 0; i < NPT; ++i) c += (bits[i] >= mid) ? 1 : 0;
    for (int off = 32; off; off >>= 1) c += __shfl_down(c, off, 64);
    if (lane == 0) rcnt[wid] = c;
    __syncthreads();
    if (threadIdx.x == 0) {
      int tot = 0;
      for (int i = 0; i < TPD / 64; ++i) tot += rcnt[i];
      bfl = (tot >= K) ? 1 : 0;
    }
    __syncthreads();
    if (bfl) lo = mid; else hi = mid - 1;
    __syncthreads();
  }
  const unsigned Tk = lo;
  const float vk = __uint_as_float(Tk);

  float s = 0.f; int cgt = 0;
  #pragma unroll
  for (int i = 0; i < NPT; ++i) {
    if (bits[i] > Tk) { s += __uint_as_float(bits[i]); ++cgt; }
  }
  double sd = (double)s;
  for (int off = 32; off; off >>= 1) {
    sd += __shfl_down(sd, off, 64);
    cgt += __shfl_down(cgt, off, 64);
  }
  __shared__ double rs[TPD / 64];
  __shared__ int rg[TPD / 64];
  if (lane == 0) { rs[wid] = sd; rg[wid] = cgt; }
  __syncthreads();
  if (threadIdx.x == 0) {
    double S = 0.0; int CG = 0;
    for (int i = 0; i < TPD / 64; ++i) { S += rs[i]; CG += rg[i]; }
    topC[b] = S + (double)vk * (double)(K - CG);
  }
}

// ---------------- Pass D: finalize ----------------
__global__ void final_kernel(const double* __restrict__ accL,
                             const double* __restrict__ accC,
                             const double* __restrict__ topC,
                             const int* __restrict__ num_pos,
                             float* __restrict__ out) {
  if (threadIdx.x == 0) {
    int n = 0;
    double sl = 0.0, sctot = 0.0;
    for (int i = 0; i < BB; ++i) {
      n += num_pos[i];
      sl += accL[i];
      sctot += accC[i] + topC[i];
    }
    double N = (double)max(n, 1);
    out[0] = (float)(sl / N);
    out[1] = (float)(sctot / N);
  }
}

extern "C" void kernel_launch(void* const* d_in, const int* in_sizes, int n_in,
                              void* d_out, int out_size, void* d_ws, size_t ws_size,
                              hipStream_t stream) {
  const float* loc     = (const float*)d_in[0];  // B*P*4
  const float* conf    = (const float*)d_in[1];  // B*P*21
  const float* priors  = (const float*)d_in[2];  // P*4
  const float* targets = (const float*)d_in[3];  // B*O*5
  float* out = (float*)d_out;

  char* ws = (char*)d_ws;
  double* accL = (double*)(ws + OFF_ACCL);
  double* accC = (double*)(ws + OFF_ACCC);
  double* topC = (double*)(ws + OFF_TOPC);
  int* num_pos = (int*)(ws + OFF_NP);
  unsigned long long* keys = (unsigned long long*)(ws + OFF_KEYS);
  float* lh = (float*)(ws + OFF_LH);

  hipMemsetAsync(ws, 0, 12288, stream);

  dim3 gridM(MB, BB);
  match_kernel<<<gridM, MT, 0, stream>>>(priors, targets, keys);
  dim3 gridL((PP + TPB - 1) / TPB, BB);
  loss_kernel<<<gridL, TPB, 0, stream>>>(loc, conf, priors, targets, keys,
                                         lh, accL, accC, num_pos);
  topk_kernel<<<BB, TPD, 0, stream>>>(lh, num_pos, topC);
  final_kernel<<<1, 64, 0, stream>>>(accL, accC, topC, num_pos, out);
}